// Round 4
// baseline (264.972 us; speedup 1.0000x reference)
//
#include <hip/hip_runtime.h>
#include <stdint.h>

#define N_CELL 8192
#define N_DRUG 4096
#define E_CELL 262144
#define E_DRUG 131072
#define DOUT   128

typedef float f32x4 __attribute__((ext_vector_type(4)));
typedef short s16x8 __attribute__((ext_vector_type(8)));

// ---------------- workspace layout (float32 element offsets) ----------------
#define OFF_DEG_C   0u          // 8192  (becomes dinv in place)
#define OFF_DEG_D   8192u       // 4096
#define OFF_CNT_C   12288u      // 8192  (int)
#define OFF_CNT_D   20480u      // 4096  (int)
#define OFF_CUR_C   24576u      // 8192  (int)
#define OFF_CUR_D   32768u      // 4096  (int)
#define OFF_START_C 36864u      // 8193  (int, padded to 8448)
#define OFF_START_D 45312u      // 4097  (int, padded to 4352)
#define OFF_EW_C    49664u      // 262144
#define OFF_EW_D    311808u     // 131072
#define OFF_SROW_C  442880u     // 262144 (int)
#define OFF_SROW_D  705024u     // 131072 (int)
#define OFF_SCOEF_C 836096u     // 262144
#define OFF_SCOEF_D 1098240u    // 131072
#define OFF_H_C     1229312u    // 8192*128
#define OFF_H_D     2277888u    // 4096*128
#define OFF_END     2802176u
#define WT_C_BYTE   (OFF_END * 4u)                    // bf16 W^T cell: 128*8192*2 B
#define WT_D_BYTE   (WT_C_BYTE + 128u * 8192u * 2u)   // bf16 W^T drug: 128*4096*2 B

__device__ __forceinline__ unsigned short f2bf(float f) {
    union { float f; uint32_t u; } v; v.f = f;
    uint32_t u = v.u + 0x7fffu + ((v.u >> 16) & 1u);   // RNE
    return (unsigned short)(u >> 16);
}

// pack 8 f32 -> 8 bf16 (round-half-up) via v_perm: 2 add + 1 perm per pair
__device__ __forceinline__ s16x8 pack8(float4 x, float4 y) {
    union { float4 f; uint32_t u[4]; } a, b;
    a.f = x; b.f = y;
    union { uint32_t u[4]; s16x8 v; } r;
    r.u[0] = __builtin_amdgcn_perm(a.u[1] + 0x8000u, a.u[0] + 0x8000u, 0x07060302u);
    r.u[1] = __builtin_amdgcn_perm(a.u[3] + 0x8000u, a.u[2] + 0x8000u, 0x07060302u);
    r.u[2] = __builtin_amdgcn_perm(b.u[1] + 0x8000u, b.u[0] + 0x8000u, 0x07060302u);
    r.u[3] = __builtin_amdgcn_perm(b.u[3] + 0x8000u, b.u[2] + 0x8000u, 0x07060302u);
    return r.v;
}

// ---------------- K1: prep = init counters + zero h + build WT bf16 ----------------
// blocks [0,144): init deg=1/cnt=0/cur=0 ; [144,1680): zero h ; [1680,3216): WT transpose
__global__ __launch_bounds__(256) void k_prep(const float* __restrict__ Wc, const float* __restrict__ Wd,
                                              unsigned short* __restrict__ wtc, unsigned short* __restrict__ wtd,
                                              float* __restrict__ ws) {
    int bid = blockIdx.x, t = threadIdx.x;
    if (bid < 144) {
        int i = bid * 256 + t;
        ws[i] = (i < 12288) ? 1.0f : 0.0f;   // deg:=1 (self loop); cnt/cur := 0 bits
        return;
    }
    if (bid < 1680) {
        size_t i = (size_t)(bid - 144) * 256 + t;
        ((float4*)(ws + OFF_H_C))[i] = make_float4(0.f, 0.f, 0.f, 0.f);
        return;
    }
    int tile = bid - 1680;
    const float* W; unsigned short* wt; int K;
    if (tile < 1024) { W = Wc; wt = wtc; K = N_CELL; }
    else             { W = Wd; wt = wtd; K = N_DRUG; tile -= 1024; }
    int tk = tile >> 2, tc = tile & 3;
    __shared__ float tl[32][33];
    int c = t & 31, r8 = t >> 5;
#pragma unroll
    for (int p = 0; p < 4; ++p) {
        int row = r8 + p * 8;
        tl[row][c] = W[(size_t)(tk * 32 + row) * DOUT + tc * 32 + c];
    }
    __syncthreads();
#pragma unroll
    for (int p = 0; p < 4; ++p) {
        int c2 = r8 + p * 8;
        wt[(size_t)(tc * 32 + c2) * K + tk * 32 + c] = f2bf(tl[c][c2]);
    }
}

// ---------------- K2: ew gather + deg atomic + incoming-edge count ----------------
__global__ __launch_bounds__(256) void k_edge(const float* __restrict__ xc, const int* __restrict__ ec,
                                              const float* __restrict__ xd, const int* __restrict__ ed,
                                              float* __restrict__ ws) {
    int i = blockIdx.x * 256 + threadIdx.x;
    const float* x; const int* edges; float* ew; float* deg; int* cnt; int N, E, idx;
    if (i < E_CELL) {
        idx = i; x = xc; edges = ec; N = N_CELL; E = E_CELL;
        ew = ws + OFF_EW_C; deg = ws + OFF_DEG_C; cnt = (int*)(ws + OFF_CNT_C);
    } else {
        idx = i - E_CELL; if (idx >= E_DRUG) return;
        x = xd; edges = ed; N = N_DRUG; E = E_DRUG;
        ew = ws + OFF_EW_D; deg = ws + OFF_DEG_D; cnt = (int*)(ws + OFF_CNT_D);
    }
    int r = edges[idx], c = edges[E + idx];
    float w = x[(size_t)r * N + c];
    ew[idx] = w;
    unsafeAtomicAdd(&deg[c], w);
    atomicAdd(&cnt[c], 1);
}

// ---------------- K3: dinv (blocks 0..47) + exclusive scan (blocks 48,49) ----------------
__global__ __launch_bounds__(256) void k_scan2(float* ws) {
    int bid = blockIdx.x, t = threadIdx.x;
    if (bid < 48) {
        int i = bid * 256 + t;
        float d = ws[i];
        ws[i] = d > 0.f ? rsqrtf(fmaxf(d, 1e-30f)) : 0.f;
        return;
    }
    const int* cnt; int* start; int N, chunk;
    if (bid == 48) { cnt = (const int*)(ws + OFF_CNT_C); start = (int*)(ws + OFF_START_C); N = N_CELL; chunk = 32; }
    else           { cnt = (const int*)(ws + OFF_CNT_D); start = (int*)(ws + OFF_START_D); N = N_DRUG; chunk = 16; }
    __shared__ int sums[256];
    int base = t * chunk;
    int s = 0;
    for (int j = 0; j < chunk; ++j) s += cnt[base + j];
    sums[t] = s; __syncthreads();
    for (int off = 1; off < 256; off <<= 1) {
        int v = (t >= off) ? sums[t - off] : 0;
        __syncthreads();
        sums[t] += v;
        __syncthreads();
    }
    int run = sums[t] - s;
    for (int j = 0; j < chunk; ++j) { start[base + j] = run; run += cnt[base + j]; }
    if (t == 255) start[N] = run;
}

// ---------------- K4: GEMM (no-LDS, direct MFMA) + CSR fill co-scheduled ----------------
// gemm: wave tile 32 rows x 128 cols; block = 4 waves = 128 rows x K-chunk 512.
// cell: 64 mt x 16 ch = 1024 blocks; drug: 32 mt x 8 ch = 256; fill: 1536 blocks.
// A read once from HBM (rows 128B-contiguous per instr); B = WT, L2-resident, per-lane frags.
// No LDS, no barriers -> compiler pipelines loads across K-steps freely.
__global__ __launch_bounds__(256) void k_gemmfill(const float* __restrict__ xc, const float* __restrict__ xd,
                                                  const unsigned short* __restrict__ wtc,
                                                  const unsigned short* __restrict__ wtd,
                                                  const int* __restrict__ ec, const int* __restrict__ ed,
                                                  float* __restrict__ ws) {
    int bid = blockIdx.x, t = threadIdx.x;
    if (bid >= 1280) {
        // ---------------- CSR fill path ----------------
        int i = (bid - 1280) * 256 + t;
        const int* edges; const float* ew; const float* dinv; const int* start;
        int* cur; int* srow; float* scoef; int E, idx;
        if (i < E_CELL) {
            idx = i; edges = ec; E = E_CELL;
            ew = ws + OFF_EW_C; dinv = ws + OFF_DEG_C; start = (const int*)(ws + OFF_START_C);
            cur = (int*)(ws + OFF_CUR_C); srow = (int*)(ws + OFF_SROW_C); scoef = ws + OFF_SCOEF_C;
        } else {
            idx = i - E_CELL; if (idx >= E_DRUG) return;
            edges = ed; E = E_DRUG;
            ew = ws + OFF_EW_D; dinv = ws + OFF_DEG_D; start = (const int*)(ws + OFF_START_D);
            cur = (int*)(ws + OFF_CUR_D); srow = (int*)(ws + OFF_SROW_D); scoef = ws + OFF_SCOEF_D;
        }
        int r = edges[idx], c = edges[E + idx];
        float coef = dinv[r] * ew[idx] * dinv[c];
        int slot = start[c] + atomicAdd(&cur[c], 1);
        srow[slot] = r;
        scoef[slot] = coef;
        return;
    }
    // ---------------- GEMM path ----------------
    const float* x; const unsigned short* wt; float* h; int K, mt, ch;
    if (bid < 1024) { x = xc; wt = wtc; h = ws + OFF_H_C; K = N_CELL; mt = bid >> 4; ch = bid & 15; }
    else { int b = bid - 1024; x = xd; wt = wtd; h = ws + OFF_H_D; K = N_DRUG; mt = b >> 3; ch = b & 7; }

    int lane = t & 63, wv = t >> 6;
    int l15 = lane & 15, l4 = lane >> 4;
    int row0 = mt * 128 + wv * 32;
    int k0 = ch << 9;                                    // K-chunk base (512)

    f32x4 acc[2][8] = {};

    const float* ap0 = x + (size_t)(row0 + l15) * K + k0 + l4 * 8;          // m=0 base
    const float* ap1 = ap0 + (size_t)16 * K;                                // m=1 base
    const unsigned short* bp = wt + (size_t)l15 * K + k0 + l4 * 8;          // n=0 base

#pragma unroll 1
    for (int kt = 0; kt < 8; ++kt) {
        int kb = kt * 64;
        // ---- load B fragments (16 x dwordx4, L2-resident) ----
        s16x8 b[8][2];
#pragma unroll
        for (int n = 0; n < 8; ++n)
#pragma unroll
            for (int kk = 0; kk < 2; ++kk)
                b[n][kk] = *(const s16x8*)(bp + (size_t)n * 16 * K + kb + kk * 32);
        // ---- load + convert A fragments (8 x dwordx4 from HBM) ----
        s16x8 a[2][2];
#pragma unroll
        for (int kk = 0; kk < 2; ++kk) {
            const float4* p0 = (const float4*)(ap0 + kb + kk * 32);
            const float4* p1 = (const float4*)(ap1 + kb + kk * 32);
            a[0][kk] = pack8(p0[0], p0[1]);
            a[1][kk] = pack8(p1[0], p1[1]);
        }
        // ---- 32 MFMA ----
#pragma unroll
        for (int kk = 0; kk < 2; ++kk)
#pragma unroll
            for (int m = 0; m < 2; ++m)
#pragma unroll
                for (int n = 0; n < 8; ++n)
                    acc[m][n] = __builtin_amdgcn_mfma_f32_16x16x32_bf16(a[m][kk], b[n][kk], acc[m][n], 0, 0, 0);
    }
    // ---- epilogue: atomic-accumulate partials. D layout: col=lane&15, row=(lane>>4)*4+j ----
#pragma unroll
    for (int m = 0; m < 2; ++m)
#pragma unroll
        for (int n = 0; n < 8; ++n) {
            int col  = n * 16 + l15;
            int row  = row0 + m * 16 + l4 * 4;
#pragma unroll
            for (int j = 0; j < 4; ++j)
                unsafeAtomicAdd(&h[(size_t)(row + j) * DOUT + col], acc[m][n][j]);
        }
}

// ---------------- K5: CSR gather + self loop + bias + relu ----------------
__global__ __launch_bounds__(256) void k_gather(const float* __restrict__ ws,
                                                const float* __restrict__ bc, const float* __restrict__ bd,
                                                float* __restrict__ out) {
    int wv = threadIdx.x >> 6, lane = threadIdx.x & 63;
    int g = blockIdx.x * 4 + wv;
    const float* h; const int* srow; const float* scoef; const int* start; const float* dinv;
    const float* bvec; float* outp; int node;
    if (g < N_CELL) {
        node = g; h = ws + OFF_H_C; srow = (const int*)(ws + OFF_SROW_C); scoef = ws + OFF_SCOEF_C;
        start = (const int*)(ws + OFF_START_C); dinv = ws + OFF_DEG_C; bvec = bc; outp = out;
    } else {
        node = g - N_CELL; if (node >= N_DRUG) return;
        h = ws + OFF_H_D; srow = (const int*)(ws + OFF_SROW_D); scoef = ws + OFF_SCOEF_D;
        start = (const int*)(ws + OFF_START_D); dinv = ws + OFF_DEG_D; bvec = bd;
        outp = out + (size_t)N_CELL * DOUT;
    }
    float di = dinv[node], sc = di * di;
    float2 v = ((const float2*)(h + (size_t)node * DOUT))[lane];
    float ax = sc * v.x, ay = sc * v.y;
    int s0 = start[node], s1 = start[node + 1];
    int e = s0;
    for (; e + 3 < s1; e += 4) {
        int r0 = srow[e];     float c0 = scoef[e];
        int r1 = srow[e + 1]; float c1 = scoef[e + 1];
        int r2 = srow[e + 2]; float c2 = scoef[e + 2];
        int r3 = srow[e + 3]; float c3 = scoef[e + 3];
        float2 u0 = ((const float2*)(h + (size_t)r0 * DOUT))[lane];
        float2 u1 = ((const float2*)(h + (size_t)r1 * DOUT))[lane];
        float2 u2 = ((const float2*)(h + (size_t)r2 * DOUT))[lane];
        float2 u3 = ((const float2*)(h + (size_t)r3 * DOUT))[lane];
        ax += c0 * u0.x + c1 * u1.x + c2 * u2.x + c3 * u3.x;
        ay += c0 * u0.y + c1 * u1.y + c2 * u2.y + c3 * u3.y;
    }
    for (; e < s1; ++e) {
        int r = srow[e]; float cf = scoef[e];
        float2 u = ((const float2*)(h + (size_t)r * DOUT))[lane];
        ax += cf * u.x; ay += cf * u.y;
    }
    float2 bb = ((const float2*)bvec)[lane];
    ax = fmaxf(ax + bb.x, 0.f);
    ay = fmaxf(ay + bb.y, 0.f);
    float2 o; o.x = ax; o.y = ay;
    ((float2*)outp)[(size_t)node * 64 + lane] = o;
}

// ---------------- host ----------------
extern "C" void kernel_launch(void* const* d_in, const int* in_sizes, int n_in,
                              void* d_out, int out_size, void* d_ws, size_t ws_size,
                              hipStream_t stream) {
    const float* cell_feat = (const float*)d_in[0];
    const int*   cell_edge = (const int*)d_in[1];
    const float* W_cell    = (const float*)d_in[2];
    const float* b_cell    = (const float*)d_in[3];
    const float* drug_feat = (const float*)d_in[4];
    const int*   drug_edge = (const int*)d_in[5];
    const float* W_drug    = (const float*)d_in[6];
    const float* b_drug    = (const float*)d_in[7];
    float* out = (float*)d_out;
    float* ws  = (float*)d_ws;
    unsigned short* wtc = (unsigned short*)((char*)d_ws + WT_C_BYTE);
    unsigned short* wtd = (unsigned short*)((char*)d_ws + WT_D_BYTE);

    k_prep<<<3216, 256, 0, stream>>>(W_cell, W_drug, wtc, wtd, ws);
    k_edge<<<(E_CELL + E_DRUG) / 256, 256, 0, stream>>>(cell_feat, cell_edge, drug_feat, drug_edge, ws);
    k_scan2<<<50, 256, 0, stream>>>(ws);
    k_gemmfill<<<2816, 256, 0, stream>>>(cell_feat, drug_feat, wtc, wtd, cell_edge, drug_edge, ws);
    k_gather<<<3072, 256, 0, stream>>>(ws, b_cell, b_drug, out);
}

// Round 5
// 264.847 us; speedup vs baseline: 1.0005x; 1.0005x over previous
//
#include <hip/hip_runtime.h>
#include <stdint.h>

#define N_CELL 8192
#define N_DRUG 4096
#define E_CELL 262144
#define E_DRUG 131072
#define DOUT   128

typedef float f32x4 __attribute__((ext_vector_type(4)));
typedef short s16x8 __attribute__((ext_vector_type(8)));

// ---------------- workspace layout (float32 element offsets) ----------------
#define OFF_DEG_C   0u          // 8192  (becomes dinv in place)
#define OFF_DEG_D   8192u       // 4096
#define OFF_CNT_C   12288u      // 8192  (int)
#define OFF_CNT_D   20480u      // 4096  (int)
#define OFF_CUR_C   24576u      // 8192  (int)
#define OFF_CUR_D   32768u      // 4096  (int)
#define OFF_START_C 36864u      // 8193  (int, padded to 8448)
#define OFF_START_D 45312u      // 4097  (int, padded to 4352)
#define OFF_EW_C    49664u      // 262144
#define OFF_EW_D    311808u     // 131072
#define OFF_SROW_C  442880u     // 262144 (int)
#define OFF_SROW_D  705024u     // 131072 (int)
#define OFF_SCOEF_C 836096u     // 262144
#define OFF_SCOEF_D 1098240u    // 131072
#define OFF_H_C     1229312u    // 8192*128
#define OFF_H_D     2277888u    // 4096*128
#define OFF_END     2802176u
#define WT_C_BYTE   (OFF_END * 4u)                    // bf16 W^T cell: 128*8192*2 B
#define WT_D_BYTE   (WT_C_BYTE + 128u * 8192u * 2u)   // bf16 W^T drug: 128*4096*2 B

__device__ __forceinline__ unsigned short f2bf(float f) {
    union { float f; uint32_t u; } v; v.f = f;
    uint32_t u = v.u + 0x7fffu + ((v.u >> 16) & 1u);   // RNE
    return (unsigned short)(u >> 16);
}

// pack 8 f32 -> 8 bf16 (round-half-up) via v_perm: 2 add + 1 perm per pair
__device__ __forceinline__ s16x8 pack8(float4 x, float4 y) {
    union { float4 f; uint32_t u[4]; } a, b;
    a.f = x; b.f = y;
    union { uint32_t u[4]; s16x8 v; } r;
    r.u[0] = __builtin_amdgcn_perm(a.u[1] + 0x8000u, a.u[0] + 0x8000u, 0x07060302u);
    r.u[1] = __builtin_amdgcn_perm(a.u[3] + 0x8000u, a.u[2] + 0x8000u, 0x07060302u);
    r.u[2] = __builtin_amdgcn_perm(b.u[1] + 0x8000u, b.u[0] + 0x8000u, 0x07060302u);
    r.u[3] = __builtin_amdgcn_perm(b.u[3] + 0x8000u, b.u[2] + 0x8000u, 0x07060302u);
    return r.v;
}

// ---------------- K1: prep = init counters + zero h + build WT bf16 ----------------
// blocks [0,144): init deg=1/cnt=0/cur=0 ; [144,1680): zero h ; [1680,3216): WT transpose
__global__ __launch_bounds__(256) void k_prep(const float* __restrict__ Wc, const float* __restrict__ Wd,
                                              unsigned short* __restrict__ wtc, unsigned short* __restrict__ wtd,
                                              float* __restrict__ ws) {
    int bid = blockIdx.x, t = threadIdx.x;
    if (bid < 144) {
        int i = bid * 256 + t;
        ws[i] = (i < 12288) ? 1.0f : 0.0f;   // deg:=1 (self loop); cnt/cur := 0 bits
        return;
    }
    if (bid < 1680) {
        size_t i = (size_t)(bid - 144) * 256 + t;
        ((float4*)(ws + OFF_H_C))[i] = make_float4(0.f, 0.f, 0.f, 0.f);
        return;
    }
    int tile = bid - 1680;
    const float* W; unsigned short* wt; int K;
    if (tile < 1024) { W = Wc; wt = wtc; K = N_CELL; }
    else             { W = Wd; wt = wtd; K = N_DRUG; tile -= 1024; }
    int tk = tile >> 2, tc = tile & 3;
    __shared__ float tl[32][33];
    int c = t & 31, r8 = t >> 5;
#pragma unroll
    for (int p = 0; p < 4; ++p) {
        int row = r8 + p * 8;
        tl[row][c] = W[(size_t)(tk * 32 + row) * DOUT + tc * 32 + c];
    }
    __syncthreads();
#pragma unroll
    for (int p = 0; p < 4; ++p) {
        int c2 = r8 + p * 8;
        wt[(size_t)(tc * 32 + c2) * K + tk * 32 + c] = f2bf(tl[c][c2]);
    }
}

// ---------------- K2: ew gather + deg atomic + incoming-edge count ----------------
__global__ __launch_bounds__(256) void k_edge(const float* __restrict__ xc, const int* __restrict__ ec,
                                              const float* __restrict__ xd, const int* __restrict__ ed,
                                              float* __restrict__ ws) {
    int i = blockIdx.x * 256 + threadIdx.x;
    const float* x; const int* edges; float* ew; float* deg; int* cnt; int N, E, idx;
    if (i < E_CELL) {
        idx = i; x = xc; edges = ec; N = N_CELL; E = E_CELL;
        ew = ws + OFF_EW_C; deg = ws + OFF_DEG_C; cnt = (int*)(ws + OFF_CNT_C);
    } else {
        idx = i - E_CELL; if (idx >= E_DRUG) return;
        x = xd; edges = ed; N = N_DRUG; E = E_DRUG;
        ew = ws + OFF_EW_D; deg = ws + OFF_DEG_D; cnt = (int*)(ws + OFF_CNT_D);
    }
    int r = edges[idx], c = edges[E + idx];
    float w = x[(size_t)r * N + c];
    ew[idx] = w;
    unsafeAtomicAdd(&deg[c], w);
    atomicAdd(&cnt[c], 1);
}

// ---------------- K3: dinv (blocks 0..47) + exclusive scan (blocks 48,49) ----------------
__global__ __launch_bounds__(256) void k_scan2(float* ws) {
    int bid = blockIdx.x, t = threadIdx.x;
    if (bid < 48) {
        int i = bid * 256 + t;
        float d = ws[i];
        ws[i] = d > 0.f ? rsqrtf(fmaxf(d, 1e-30f)) : 0.f;
        return;
    }
    const int* cnt; int* start; int N, chunk;
    if (bid == 48) { cnt = (const int*)(ws + OFF_CNT_C); start = (int*)(ws + OFF_START_C); N = N_CELL; chunk = 32; }
    else           { cnt = (const int*)(ws + OFF_CNT_D); start = (int*)(ws + OFF_START_D); N = N_DRUG; chunk = 16; }
    __shared__ int sums[256];
    int base = t * chunk;
    int s = 0;
    for (int j = 0; j < chunk; ++j) s += cnt[base + j];
    sums[t] = s; __syncthreads();
    for (int off = 1; off < 256; off <<= 1) {
        int v = (t >= off) ? sums[t - off] : 0;
        __syncthreads();
        sums[t] += v;
        __syncthreads();
    }
    int run = sums[t] - s;
    for (int j = 0; j < chunk; ++j) { start[base + j] = run; run += cnt[base + j]; }
    if (t == 255) start[N] = run;
}

// ---------------- K4: GEMM (B in LDS per sub-chunk, A reg-prefetched) + CSR fill ----------------
// Block = 128 rows x 128 cols x K-chunk 1024; 4 sub-chunks of 256 K.
// Per sub-chunk: stage WT[128 cols][256 k] -> 64 KB LDS (swizzled), 2 barriers;
// then 4 K-steps of 64 with A direct-from-HBM, 1-deep X/Y register prefetch (counted vmcnt).
// Wave tile 32 rows x 128 cols; acc[2][8]. Atomic-accumulate into pre-zeroed h.
// cell: 64 mt x 8 ch = 512 blocks; drug: 32 mt x 4 ch = 128; fill: 1536. Grid 2176.
__global__ __launch_bounds__(256, 2) void k_gemmfill(const float* __restrict__ xc, const float* __restrict__ xd,
                                                      const unsigned short* __restrict__ wtc,
                                                      const unsigned short* __restrict__ wtd,
                                                      const int* __restrict__ ec, const int* __restrict__ ed,
                                                      float* __restrict__ ws) {
    int bid = blockIdx.x, t = threadIdx.x;
    if (bid >= 640) {
        // ---------------- CSR fill path ----------------
        int i = (bid - 640) * 256 + t;
        const int* edges; const float* ew; const float* dinv; const int* start;
        int* cur; int* srow; float* scoef; int E, idx;
        if (i < E_CELL) {
            idx = i; edges = ec; E = E_CELL;
            ew = ws + OFF_EW_C; dinv = ws + OFF_DEG_C; start = (const int*)(ws + OFF_START_C);
            cur = (int*)(ws + OFF_CUR_C); srow = (int*)(ws + OFF_SROW_C); scoef = ws + OFF_SCOEF_C;
        } else {
            idx = i - E_CELL; if (idx >= E_DRUG) return;
            edges = ed; E = E_DRUG;
            ew = ws + OFF_EW_D; dinv = ws + OFF_DEG_D; start = (const int*)(ws + OFF_START_D);
            cur = (int*)(ws + OFF_CUR_D); srow = (int*)(ws + OFF_SROW_D); scoef = ws + OFF_SCOEF_D;
        }
        int r = edges[idx], c = edges[E + idx];
        float coef = dinv[r] * ew[idx] * dinv[c];
        int slot = start[c] + atomicAdd(&cur[c], 1);
        srow[slot] = r;
        scoef[slot] = coef;
        return;
    }
    // ---------------- GEMM path ----------------
    const float* x; const unsigned short* wt; float* h; int K, mt, ch;
    if (bid < 512) { x = xc; wt = wtc; h = ws + OFF_H_C; K = N_CELL; mt = bid >> 3; ch = bid & 7; }
    else { int b = bid - 512; x = xd; wt = wtd; h = ws + OFF_H_D; K = N_DRUG; mt = b >> 2; ch = b & 3; }

    __shared__ alignas(16) unsigned char smem[65536];
    int lane = t & 63, wv = t >> 6;
    int l15 = lane & 15, l4 = lane >> 4;
    int row0 = mt * 128 + wv * 32;
    int kch = ch << 10;                                  // K-chunk base (1024)
    unsigned swx = (unsigned)(l15 & 7) << 4;             // read-side XOR

    f32x4 acc[2][8] = {};

    // A per-lane bases: row = row0 + m*16 + l15, k starts at kch + l4*8
    const float* apm0 = x + (size_t)(row0 + l15) * K + kch + l4 * 8;
    const float* apm1 = apm0 + (size_t)16 * K;

    // B staging mapping: thread covers col c = t&127, k-half kh = t>>7 (128 k each)
    int bc = t & 127, bkh = t >> 7;
    const unsigned short* bsrc = wt + (size_t)bc * K + kch + bkh * 128;
    unsigned bswb = ((unsigned)bc << 9) + ((unsigned)bkh << 8);
    unsigned bswx = (unsigned)(bc & 7) << 4;

    float4 X[8], Y[8];

#define LOADA(R, SC, KT) { \
    const float4* p0 = (const float4*)(apm0 + (SC) * 256 + (KT) * 64); \
    const float4* p1 = (const float4*)(apm0 + (SC) * 256 + (KT) * 64 + 32); \
    const float4* p2 = (const float4*)(apm1 + (SC) * 256 + (KT) * 64); \
    const float4* p3 = (const float4*)(apm1 + (SC) * 256 + (KT) * 64 + 32); \
    R[0] = p0[0]; R[1] = p0[1]; R[2] = p1[0]; R[3] = p1[1]; \
    R[4] = p2[0]; R[5] = p2[1]; R[6] = p3[0]; R[7] = p3[1]; }

#define COMPUTE(R, KT) { \
    s16x8 a00 = pack8(R[0], R[1]), a01 = pack8(R[2], R[3]); \
    s16x8 a10 = pack8(R[4], R[5]), a11 = pack8(R[6], R[7]); \
    _Pragma("unroll") for (int n = 0; n < 8; ++n) { \
        unsigned cb = (unsigned)(n * 16 + l15) << 9; \
        s16x8 b0 = *(const s16x8*)&smem[(cb + (((KT) * 64 + l4 * 8) << 1)) ^ swx]; \
        s16x8 b1 = *(const s16x8*)&smem[(cb + (((KT) * 64 + 32 + l4 * 8) << 1)) ^ swx]; \
        acc[0][n] = __builtin_amdgcn_mfma_f32_16x16x32_bf16(a00, b0, acc[0][n], 0, 0, 0); \
        acc[1][n] = __builtin_amdgcn_mfma_f32_16x16x32_bf16(a10, b0, acc[1][n], 0, 0, 0); \
        acc[0][n] = __builtin_amdgcn_mfma_f32_16x16x32_bf16(a01, b1, acc[0][n], 0, 0, 0); \
        acc[1][n] = __builtin_amdgcn_mfma_f32_16x16x32_bf16(a11, b1, acc[1][n], 0, 0, 0); \
    } }

#pragma unroll 1
    for (int sc = 0; sc < 4; ++sc) {
        __syncthreads();                                  // prev sub-chunk's LDS reads done
        // ---- stage B[128 cols][256 k] bf16 into LDS, swizzled ----
#pragma unroll
        for (int j = 0; j < 16; ++j) {
            s16x8 v = *(const s16x8*)(bsrc + sc * 256 + j * 8);
            *(s16x8*)&smem[(bswb + (unsigned)j * 16) ^ bswx] = v;
        }
        __syncthreads();                                  // B visible
        // ---- 4 K-steps, 1-deep A prefetch (X/Y ping-pong, all static) ----
        LOADA(X, sc, 0); LOADA(Y, sc, 1);
        COMPUTE(X, 0);   LOADA(X, sc, 2);
        COMPUTE(Y, 1);   LOADA(Y, sc, 3);
        COMPUTE(X, 2);
        COMPUTE(Y, 3);
    }
#undef LOADA
#undef COMPUTE
    // ---- epilogue: atomic-accumulate partials. D layout: col=lane&15, row=(lane>>4)*4+j ----
#pragma unroll
    for (int m = 0; m < 2; ++m)
#pragma unroll
        for (int n = 0; n < 8; ++n) {
            int col = n * 16 + l15;
            int row = row0 + m * 16 + l4 * 4;
#pragma unroll
            for (int j = 0; j < 4; ++j)
                unsafeAtomicAdd(&h[(size_t)(row + j) * DOUT + col], acc[m][n][j]);
        }
}

// ---------------- K5: CSR gather + self loop + bias + relu ----------------
__global__ __launch_bounds__(256) void k_gather(const float* __restrict__ ws,
                                                const float* __restrict__ bc, const float* __restrict__ bd,
                                                float* __restrict__ out) {
    int wv = threadIdx.x >> 6, lane = threadIdx.x & 63;
    int g = blockIdx.x * 4 + wv;
    const float* h; const int* srow; const float* scoef; const int* start; const float* dinv;
    const float* bvec; float* outp; int node;
    if (g < N_CELL) {
        node = g; h = ws + OFF_H_C; srow = (const int*)(ws + OFF_SROW_C); scoef = ws + OFF_SCOEF_C;
        start = (const int*)(ws + OFF_START_C); dinv = ws + OFF_DEG_C; bvec = bc; outp = out;
    } else {
        node = g - N_CELL; if (node >= N_DRUG) return;
        h = ws + OFF_H_D; srow = (const int*)(ws + OFF_SROW_D); scoef = ws + OFF_SCOEF_D;
        start = (const int*)(ws + OFF_START_D); dinv = ws + OFF_DEG_D; bvec = bd;
        outp = out + (size_t)N_CELL * DOUT;
    }
    float di = dinv[node], sc = di * di;
    float2 v = ((const float2*)(h + (size_t)node * DOUT))[lane];
    float ax = sc * v.x, ay = sc * v.y;
    int s0 = start[node], s1 = start[node + 1];
    int e = s0;
    for (; e + 3 < s1; e += 4) {
        int r0 = srow[e];     float c0 = scoef[e];
        int r1 = srow[e + 1]; float c1 = scoef[e + 1];
        int r2 = srow[e + 2]; float c2 = scoef[e + 2];
        int r3 = srow[e + 3]; float c3 = scoef[e + 3];
        float2 u0 = ((const float2*)(h + (size_t)r0 * DOUT))[lane];
        float2 u1 = ((const float2*)(h + (size_t)r1 * DOUT))[lane];
        float2 u2 = ((const float2*)(h + (size_t)r2 * DOUT))[lane];
        float2 u3 = ((const float2*)(h + (size_t)r3 * DOUT))[lane];
        ax += c0 * u0.x + c1 * u1.x + c2 * u2.x + c3 * u3.x;
        ay += c0 * u0.y + c1 * u1.y + c2 * u2.y + c3 * u3.y;
    }
    for (; e < s1; ++e) {
        int r = srow[e]; float cf = scoef[e];
        float2 u = ((const float2*)(h + (size_t)r * DOUT))[lane];
        ax += cf * u.x; ay += cf * u.y;
    }
    float2 bb = ((const float2*)bvec)[lane];
    ax = fmaxf(ax + bb.x, 0.f);
    ay = fmaxf(ay + bb.y, 0.f);
    float2 o; o.x = ax; o.y = ay;
    ((float2*)outp)[(size_t)node * 64 + lane] = o;
}

// ---------------- host ----------------
extern "C" void kernel_launch(void* const* d_in, const int* in_sizes, int n_in,
                              void* d_out, int out_size, void* d_ws, size_t ws_size,
                              hipStream_t stream) {
    const float* cell_feat = (const float*)d_in[0];
    const int*   cell_edge = (const int*)d_in[1];
    const float* W_cell    = (const float*)d_in[2];
    const float* b_cell    = (const float*)d_in[3];
    const float* drug_feat = (const float*)d_in[4];
    const int*   drug_edge = (const int*)d_in[5];
    const float* W_drug    = (const float*)d_in[6];
    const float* b_drug    = (const float*)d_in[7];
    float* out = (float*)d_out;
    float* ws  = (float*)d_ws;
    unsigned short* wtc = (unsigned short*)((char*)d_ws + WT_C_BYTE);
    unsigned short* wtd = (unsigned short*)((char*)d_ws + WT_D_BYTE);

    k_prep<<<3216, 256, 0, stream>>>(W_cell, W_drug, wtc, wtd, ws);
    k_edge<<<(E_CELL + E_DRUG) / 256, 256, 0, stream>>>(cell_feat, cell_edge, drug_feat, drug_edge, ws);
    k_scan2<<<50, 256, 0, stream>>>(ws);
    k_gemmfill<<<2176, 256, 0, stream>>>(cell_feat, drug_feat, wtc, wtd, cell_edge, drug_edge, ws);
    k_gather<<<3072, 256, 0, stream>>>(ws, b_cell, b_drug, out);
}

// Round 6
// 216.270 us; speedup vs baseline: 1.2252x; 1.2246x over previous
//
#include <hip/hip_runtime.h>
#include <stdint.h>

#define N_CELL 8192
#define N_DRUG 4096
#define E_CELL 262144
#define E_DRUG 131072
#define DOUT   128

typedef float f32x4 __attribute__((ext_vector_type(4)));
typedef short s16x8 __attribute__((ext_vector_type(8)));

// ---------------- workspace layout (float32 element offsets) ----------------
#define OFF_DEG_C   0u          // 8192  (becomes dinv in place)
#define OFF_DEG_D   8192u       // 4096
#define OFF_CNT_C   12288u      // 8192  (int)
#define OFF_CNT_D   20480u      // 4096  (int)
#define OFF_CUR_C   24576u      // 8192  (int)
#define OFF_CUR_D   32768u      // 4096  (int)
#define OFF_START_C 36864u      // 8193  (int, padded to 8448)
#define OFF_START_D 45312u      // 4097  (int, padded to 4352)
#define OFF_EW_C    49664u      // 262144
#define OFF_EW_D    311808u     // 131072
#define OFF_SROW_C  442880u     // 262144 (int)
#define OFF_SROW_D  705024u     // 131072 (int)
#define OFF_SCOEF_C 836096u     // 262144
#define OFF_SCOEF_D 1098240u    // 131072
#define OFF_H_C     1229312u    // 8192*128
#define OFF_H_D     2277888u    // 4096*128
#define OFF_END     2802176u
#define WT_C_BYTE   (OFF_END * 4u)                    // bf16 W^T cell: 128*8192*2 B
#define WT_D_BYTE   (WT_C_BYTE + 128u * 8192u * 2u)   // bf16 W^T drug: 128*4096*2 B

__device__ __forceinline__ unsigned short f2bf(float f) {
    union { float f; uint32_t u; } v; v.f = f;
    uint32_t u = v.u + 0x7fffu + ((v.u >> 16) & 1u);   // RNE
    return (unsigned short)(u >> 16);
}

// pack 8 f32 -> 8 bf16 (round-half-up) via v_perm: 2 add + 1 perm per pair
__device__ __forceinline__ s16x8 pack8(float4 x, float4 y) {
    union { float4 f; uint32_t u[4]; } a, b;
    a.f = x; b.f = y;
    union { uint32_t u[4]; s16x8 v; } r;
    r.u[0] = __builtin_amdgcn_perm(a.u[1] + 0x8000u, a.u[0] + 0x8000u, 0x07060302u);
    r.u[1] = __builtin_amdgcn_perm(a.u[3] + 0x8000u, a.u[2] + 0x8000u, 0x07060302u);
    r.u[2] = __builtin_amdgcn_perm(b.u[1] + 0x8000u, b.u[0] + 0x8000u, 0x07060302u);
    r.u[3] = __builtin_amdgcn_perm(b.u[3] + 0x8000u, b.u[2] + 0x8000u, 0x07060302u);
    return r.v;
}

// ---------------- K1: prep = init counters + zero h + build WT bf16 ----------------
__global__ __launch_bounds__(256) void k_prep(const float* __restrict__ Wc, const float* __restrict__ Wd,
                                              unsigned short* __restrict__ wtc, unsigned short* __restrict__ wtd,
                                              float* __restrict__ ws) {
    int bid = blockIdx.x, t = threadIdx.x;
    if (bid < 144) {
        int i = bid * 256 + t;
        ws[i] = (i < 12288) ? 1.0f : 0.0f;   // deg:=1 (self loop); cnt/cur := 0 bits
        return;
    }
    if (bid < 1680) {
        size_t i = (size_t)(bid - 144) * 256 + t;
        ((float4*)(ws + OFF_H_C))[i] = make_float4(0.f, 0.f, 0.f, 0.f);
        return;
    }
    int tile = bid - 1680;
    const float* W; unsigned short* wt; int K;
    if (tile < 1024) { W = Wc; wt = wtc; K = N_CELL; }
    else             { W = Wd; wt = wtd; K = N_DRUG; tile -= 1024; }
    int tk = tile >> 2, tc = tile & 3;
    __shared__ float tl[32][33];
    int c = t & 31, r8 = t >> 5;
#pragma unroll
    for (int p = 0; p < 4; ++p) {
        int row = r8 + p * 8;
        tl[row][c] = W[(size_t)(tk * 32 + row) * DOUT + tc * 32 + c];
    }
    __syncthreads();
#pragma unroll
    for (int p = 0; p < 4; ++p) {
        int c2 = r8 + p * 8;
        wt[(size_t)(tc * 32 + c2) * K + tk * 32 + c] = f2bf(tl[c][c2]);
    }
}

// ---------------- K2: ew gather + deg atomic + incoming-edge count ----------------
__global__ __launch_bounds__(256) void k_edge(const float* __restrict__ xc, const int* __restrict__ ec,
                                              const float* __restrict__ xd, const int* __restrict__ ed,
                                              float* __restrict__ ws) {
    int i = blockIdx.x * 256 + threadIdx.x;
    const float* x; const int* edges; float* ew; float* deg; int* cnt; int N, E, idx;
    if (i < E_CELL) {
        idx = i; x = xc; edges = ec; N = N_CELL; E = E_CELL;
        ew = ws + OFF_EW_C; deg = ws + OFF_DEG_C; cnt = (int*)(ws + OFF_CNT_C);
    } else {
        idx = i - E_CELL; if (idx >= E_DRUG) return;
        x = xd; edges = ed; N = N_DRUG; E = E_DRUG;
        ew = ws + OFF_EW_D; deg = ws + OFF_DEG_D; cnt = (int*)(ws + OFF_CNT_D);
    }
    int r = edges[idx], c = edges[E + idx];
    float w = x[(size_t)r * N + c];
    ew[idx] = w;
    unsafeAtomicAdd(&deg[c], w);
    atomicAdd(&cnt[c], 1);
}

// ---------------- K3: dinv (blocks 0..47) + exclusive scan (blocks 48,49) ----------------
__global__ __launch_bounds__(256) void k_scan2(float* ws) {
    int bid = blockIdx.x, t = threadIdx.x;
    if (bid < 48) {
        int i = bid * 256 + t;
        float d = ws[i];
        ws[i] = d > 0.f ? rsqrtf(fmaxf(d, 1e-30f)) : 0.f;
        return;
    }
    const int* cnt; int* start; int N, chunk;
    if (bid == 48) { cnt = (const int*)(ws + OFF_CNT_C); start = (int*)(ws + OFF_START_C); N = N_CELL; chunk = 32; }
    else           { cnt = (const int*)(ws + OFF_CNT_D); start = (int*)(ws + OFF_START_D); N = N_DRUG; chunk = 16; }
    __shared__ int sums[256];
    int base = t * chunk;
    int s = 0;
    for (int j = 0; j < chunk; ++j) s += cnt[base + j];
    sums[t] = s; __syncthreads();
    for (int off = 1; off < 256; off <<= 1) {
        int v = (t >= off) ? sums[t - off] : 0;
        __syncthreads();
        sums[t] += v;
        __syncthreads();
    }
    int run = sums[t] - s;
    for (int j = 0; j < chunk; ++j) { start[base + j] = run; run += cnt[base + j]; }
    if (t == 255) start[N] = run;
}

// ---------------- K4: fill CSR slots (srow, scoef) ----------------
__global__ __launch_bounds__(256) void k_fill(const int* __restrict__ ec, const int* __restrict__ ed,
                                              float* __restrict__ ws) {
    int i = blockIdx.x * 256 + threadIdx.x;
    const int* edges; const float* ew; const float* dinv; const int* start;
    int* cur; int* srow; float* scoef; int E, idx;
    if (i < E_CELL) {
        idx = i; edges = ec; E = E_CELL;
        ew = ws + OFF_EW_C; dinv = ws + OFF_DEG_C; start = (const int*)(ws + OFF_START_C);
        cur = (int*)(ws + OFF_CUR_C); srow = (int*)(ws + OFF_SROW_C); scoef = ws + OFF_SCOEF_C;
    } else {
        idx = i - E_CELL; if (idx >= E_DRUG) return;
        edges = ed; E = E_DRUG;
        ew = ws + OFF_EW_D; dinv = ws + OFF_DEG_D; start = (const int*)(ws + OFF_START_D);
        cur = (int*)(ws + OFF_CUR_D); srow = (int*)(ws + OFF_SROW_D); scoef = ws + OFF_SCOEF_D;
    }
    int r = edges[idx], c = edges[E + idx];
    float coef = dinv[r] * ew[idx] * dinv[c];
    int slot = start[c] + atomicAdd(&cur[c], 1);
    srow[slot] = r;
    scoef[slot] = coef;
}

// ---------------- K5: GEMM h = x @ W, coalesced LDS staging, k-phase rotated ----------------
// Tile 64 rows x 128 cols, BK=64, K-chunk 1024 (16 steps). LDS 24 KB: A 64x64 bf16 (8K,
// swizzled) + B 128x64 bf16 (16K, swizzled). 4 waves, each 16 rows x 128 cols, acc[8].
// cell: 128 mt x 8 ch = 1024 blocks; drug: 64 x 4 = 256. Grid 1280 = ~4-5 blocks/CU resident.
// Per step: STAGE_A(X regs) -> B loads -> A prefetch (after B in vmem queue, so B's
// counted vmcnt leaves A in flight) -> B write -> sync -> MFMA -> sync.
// k-step order rotated per block ((g*5)&15) to spread 32KB-strided row reads across channels.
#define SWA(row, bk) ((((row) << 7) + (bk)) ^ (((row) & 7) << 4))
#define SWB(col, bk) (8192 + ((((col) << 7) + (bk)) ^ (((col) & 7) << 4)))

__global__ __launch_bounds__(256, 4) void k_gemm(const float* __restrict__ xc, const float* __restrict__ xd,
                                                 const unsigned short* __restrict__ wtc,
                                                 const unsigned short* __restrict__ wtd,
                                                 float* __restrict__ ws) {
    int bid = blockIdx.x, t = threadIdx.x;
    const float* x; const unsigned short* wt; float* h; int K, mt, ch, g;
    if (bid < 1024) { g = bid; x = xc; wt = wtc; h = ws + OFF_H_C; K = N_CELL; mt = g & 127; ch = g >> 7; }
    else { g = bid - 1024; x = xd; wt = wtd; h = ws + OFF_H_D; K = N_DRUG; mt = g & 63; ch = g >> 6; }
    int phase = (g * 5) & 15;
    int kch = ch << 10;

    __shared__ alignas(16) unsigned char smem[24576];
    int lane = t & 63, wv = t >> 6;
    int l15 = lane & 15, l4 = lane >> 4;
    int wrow = wv * 16;

    f32x4 acc[8] = {};

    // A staging: thread covers row srow = t>>2, 64B segment sq = t&3 (16 consecutive f32)
    int srow = t >> 2, sq = t & 3;
    const float* abase = x + (size_t)(mt * 64 + srow) * K + kch + sq * 16;
    // B staging: thread covers col bcol = t>>1, half bhalf = t&1 (32 consecutive bf16)
    int bcol = t >> 1, bhalf = t & 1;
    const unsigned short* bbase = wt + (size_t)bcol * K + kch + bhalf * 32;

    float4 X[4], Y[4];
    s16x8 bq[4];

#define KI(i) (((i) + phase) & 15)
#define LOADA(R, KIDX) { const float4* p = (const float4*)(abase + (KIDX) * 64); \
                         R[0] = p[0]; R[1] = p[1]; R[2] = p[2]; R[3] = p[3]; }
#define STAGE_A(R) { s16x8 lo = pack8(R[0], R[1]); s16x8 hi = pack8(R[2], R[3]); \
                     *(s16x8*)&smem[SWA(srow, sq * 32)]      = lo; \
                     *(s16x8*)&smem[SWA(srow, sq * 32 + 16)] = hi; }
#define BLOAD(KIDX) { _Pragma("unroll") for (int j = 0; j < 4; ++j) \
                      bq[j] = *(const s16x8*)(bbase + (KIDX) * 64 + j * 8); }
#define BWRITE() { _Pragma("unroll") for (int j = 0; j < 4; ++j) \
                   *(s16x8*)&smem[SWB(bcol, bhalf * 64 + j * 16)] = bq[j]; }
#define MFMA_PHASE() { \
    s16x8 a0 = *(const s16x8*)&smem[SWA(wrow + l15, l4 * 16)]; \
    s16x8 a1 = *(const s16x8*)&smem[SWA(wrow + l15, 64 + l4 * 16)]; \
    _Pragma("unroll") for (int n = 0; n < 8; ++n) { \
        int col = n * 16 + l15; \
        s16x8 b0 = *(const s16x8*)&smem[SWB(col, l4 * 16)]; \
        s16x8 b1 = *(const s16x8*)&smem[SWB(col, 64 + l4 * 16)]; \
        acc[n] = __builtin_amdgcn_mfma_f32_16x16x32_bf16(a0, b0, acc[n], 0, 0, 0); \
        acc[n] = __builtin_amdgcn_mfma_f32_16x16x32_bf16(a1, b1, acc[n], 0, 0, 0); } }

    LOADA(X, KI(0));
#pragma unroll 1
    for (int kt2 = 0; kt2 < 8; ++kt2) {
        // ---- even step ----
        STAGE_A(X);
        BLOAD(KI(kt2 * 2));
        LOADA(Y, KI(kt2 * 2 + 1));       // issued after B loads: B's vmcnt leaves these in flight
        BWRITE();
        __syncthreads();
        MFMA_PHASE();
        __syncthreads();
        // ---- odd step ----
        STAGE_A(Y);
        BLOAD(KI(kt2 * 2 + 1));
        if (kt2 < 7) LOADA(X, KI(kt2 * 2 + 2));
        BWRITE();
        __syncthreads();
        MFMA_PHASE();
        __syncthreads();
    }
#undef KI
#undef LOADA
#undef STAGE_A
#undef BLOAD
#undef BWRITE
#undef MFMA_PHASE
    // ---- epilogue: atomic-accumulate partials. D layout: col=lane&15, row=(lane>>4)*4+j ----
#pragma unroll
    for (int n = 0; n < 8; ++n) {
        int col = n * 16 + l15;
        int row = mt * 64 + wrow + l4 * 4;
#pragma unroll
        for (int j = 0; j < 4; ++j)
            unsafeAtomicAdd(&h[(size_t)(row + j) * DOUT + col], acc[n][j]);
    }
}

// ---------------- K6: CSR gather + self loop + bias + relu ----------------
__global__ __launch_bounds__(256) void k_gather(const float* __restrict__ ws,
                                                const float* __restrict__ bc, const float* __restrict__ bd,
                                                float* __restrict__ out) {
    int wv = threadIdx.x >> 6, lane = threadIdx.x & 63;
    int g = blockIdx.x * 4 + wv;
    const float* h; const int* srow; const float* scoef; const int* start; const float* dinv;
    const float* bvec; float* outp; int node;
    if (g < N_CELL) {
        node = g; h = ws + OFF_H_C; srow = (const int*)(ws + OFF_SROW_C); scoef = ws + OFF_SCOEF_C;
        start = (const int*)(ws + OFF_START_C); dinv = ws + OFF_DEG_C; bvec = bc; outp = out;
    } else {
        node = g - N_CELL; if (node >= N_DRUG) return;
        h = ws + OFF_H_D; srow = (const int*)(ws + OFF_SROW_D); scoef = ws + OFF_SCOEF_D;
        start = (const int*)(ws + OFF_START_D); dinv = ws + OFF_DEG_D; bvec = bd;
        outp = out + (size_t)N_CELL * DOUT;
    }
    float di = dinv[node], sc = di * di;
    float2 v = ((const float2*)(h + (size_t)node * DOUT))[lane];
    float ax = sc * v.x, ay = sc * v.y;
    int s0 = start[node], s1 = start[node + 1];
    int e = s0;
    for (; e + 3 < s1; e += 4) {
        int r0 = srow[e];     float c0 = scoef[e];
        int r1 = srow[e + 1]; float c1 = scoef[e + 1];
        int r2 = srow[e + 2]; float c2 = scoef[e + 2];
        int r3 = srow[e + 3]; float c3 = scoef[e + 3];
        float2 u0 = ((const float2*)(h + (size_t)r0 * DOUT))[lane];
        float2 u1 = ((const float2*)(h + (size_t)r1 * DOUT))[lane];
        float2 u2 = ((const float2*)(h + (size_t)r2 * DOUT))[lane];
        float2 u3 = ((const float2*)(h + (size_t)r3 * DOUT))[lane];
        ax += c0 * u0.x + c1 * u1.x + c2 * u2.x + c3 * u3.x;
        ay += c0 * u0.y + c1 * u1.y + c2 * u2.y + c3 * u3.y;
    }
    for (; e < s1; ++e) {
        int r = srow[e]; float cf = scoef[e];
        float2 u = ((const float2*)(h + (size_t)r * DOUT))[lane];
        ax += cf * u.x; ay += cf * u.y;
    }
    float2 bb = ((const float2*)bvec)[lane];
    ax = fmaxf(ax + bb.x, 0.f);
    ay = fmaxf(ay + bb.y, 0.f);
    float2 o; o.x = ax; o.y = ay;
    ((float2*)outp)[(size_t)node * 64 + lane] = o;
}

// ---------------- host ----------------
extern "C" void kernel_launch(void* const* d_in, const int* in_sizes, int n_in,
                              void* d_out, int out_size, void* d_ws, size_t ws_size,
                              hipStream_t stream) {
    const float* cell_feat = (const float*)d_in[0];
    const int*   cell_edge = (const int*)d_in[1];
    const float* W_cell    = (const float*)d_in[2];
    const float* b_cell    = (const float*)d_in[3];
    const float* drug_feat = (const float*)d_in[4];
    const int*   drug_edge = (const int*)d_in[5];
    const float* W_drug    = (const float*)d_in[6];
    const float* b_drug    = (const float*)d_in[7];
    float* out = (float*)d_out;
    float* ws  = (float*)d_ws;
    unsigned short* wtc = (unsigned short*)((char*)d_ws + WT_C_BYTE);
    unsigned short* wtd = (unsigned short*)((char*)d_ws + WT_D_BYTE);

    k_prep<<<3216, 256, 0, stream>>>(W_cell, W_drug, wtc, wtd, ws);
    k_edge<<<(E_CELL + E_DRUG) / 256, 256, 0, stream>>>(cell_feat, cell_edge, drug_feat, drug_edge, ws);
    k_scan2<<<50, 256, 0, stream>>>(ws);
    k_fill<<<1536, 256, 0, stream>>>(cell_edge, drug_edge, ws);
    k_gemm<<<1280, 256, 0, stream>>>(cell_feat, drug_feat, wtc, wtd, ws);
    k_gather<<<3072, 256, 0, stream>>>(ws, b_cell, b_drug, out);
}

// Round 7
// 204.789 us; speedup vs baseline: 1.2939x; 1.0561x over previous
//
#include <hip/hip_runtime.h>
#include <stdint.h>

#define N_CELL 8192
#define N_DRUG 4096
#define E_CELL 262144
#define E_DRUG 131072
#define DOUT   128

typedef float f32x4 __attribute__((ext_vector_type(4)));
typedef short s16x8 __attribute__((ext_vector_type(8)));

// ---------------- workspace layout (float32 element offsets) ----------------
#define OFF_DEG_C   0u
#define OFF_DEG_D   8192u
#define OFF_CNT_C   12288u
#define OFF_CNT_D   20480u
#define OFF_CUR_C   24576u
#define OFF_CUR_D   32768u
#define OFF_START_C 36864u
#define OFF_START_D 45312u
#define OFF_EW_C    49664u
#define OFF_EW_D    311808u
#define OFF_SROW_C  442880u
#define OFF_SROW_D  705024u
#define OFF_SCOEF_C 836096u
#define OFF_SCOEF_D 1098240u
#define OFF_H_C     1229312u
#define OFF_H_D     2277888u
#define OFF_END     2802176u
#define WT_C_BYTE   (OFF_END * 4u)
#define WT_D_BYTE   (WT_C_BYTE + 128u * 8192u * 2u)

__device__ __forceinline__ unsigned short f2bf(float f) {
    union { float f; uint32_t u; } v; v.f = f;
    uint32_t u = v.u + 0x7fffu + ((v.u >> 16) & 1u);   // RNE
    return (unsigned short)(u >> 16);
}

// pack 8 f32 -> 8 bf16 (round-half-up) via v_perm: 2 add + 1 perm per pair
__device__ __forceinline__ s16x8 pack8(float4 x, float4 y) {
    union { float4 f; uint32_t u[4]; } a, b;
    a.f = x; b.f = y;
    union { uint32_t u[4]; s16x8 v; } r;
    r.u[0] = __builtin_amdgcn_perm(a.u[1] + 0x8000u, a.u[0] + 0x8000u, 0x07060302u);
    r.u[1] = __builtin_amdgcn_perm(a.u[3] + 0x8000u, a.u[2] + 0x8000u, 0x07060302u);
    r.u[2] = __builtin_amdgcn_perm(b.u[1] + 0x8000u, b.u[0] + 0x8000u, 0x07060302u);
    r.u[3] = __builtin_amdgcn_perm(b.u[3] + 0x8000u, b.u[2] + 0x8000u, 0x07060302u);
    return r.v;
}

// async global -> LDS, 16B per lane. dest = uniform base + lane*16 (linear).
__device__ __forceinline__ void gload16(const void* g, void* l) {
    __builtin_amdgcn_global_load_lds((const __attribute__((address_space(1))) void*)g,
                                     (__attribute__((address_space(3))) void*)l, 16, 0, 0);
}

// ---------------- K1: prep = init counters + zero h + build WT bf16 ----------------
__global__ __launch_bounds__(256) void k_prep(const float* __restrict__ Wc, const float* __restrict__ Wd,
                                              unsigned short* __restrict__ wtc, unsigned short* __restrict__ wtd,
                                              float* __restrict__ ws) {
    int bid = blockIdx.x, t = threadIdx.x;
    if (bid < 144) {
        int i = bid * 256 + t;
        ws[i] = (i < 12288) ? 1.0f : 0.0f;   // deg:=1 (self loop); cnt/cur := 0 bits
        return;
    }
    if (bid < 1680) {
        size_t i = (size_t)(bid - 144) * 256 + t;
        ((float4*)(ws + OFF_H_C))[i] = make_float4(0.f, 0.f, 0.f, 0.f);
        return;
    }
    int tile = bid - 1680;
    const float* W; unsigned short* wt; int K;
    if (tile < 1024) { W = Wc; wt = wtc; K = N_CELL; }
    else             { W = Wd; wt = wtd; K = N_DRUG; tile -= 1024; }
    int tk = tile >> 2, tc = tile & 3;
    __shared__ float tl[32][33];
    int c = t & 31, r8 = t >> 5;
#pragma unroll
    for (int p = 0; p < 4; ++p) {
        int row = r8 + p * 8;
        tl[row][c] = W[(size_t)(tk * 32 + row) * DOUT + tc * 32 + c];
    }
    __syncthreads();
#pragma unroll
    for (int p = 0; p < 4; ++p) {
        int c2 = r8 + p * 8;
        wt[(size_t)(tc * 32 + c2) * K + tk * 32 + c] = f2bf(tl[c][c2]);
    }
}

// ---------------- K2: ew gather + deg atomic + incoming-edge count ----------------
__global__ __launch_bounds__(256) void k_edge(const float* __restrict__ xc, const int* __restrict__ ec,
                                              const float* __restrict__ xd, const int* __restrict__ ed,
                                              float* __restrict__ ws) {
    int i = blockIdx.x * 256 + threadIdx.x;
    const float* x; const int* edges; float* ew; float* deg; int* cnt; int N, E, idx;
    if (i < E_CELL) {
        idx = i; x = xc; edges = ec; N = N_CELL; E = E_CELL;
        ew = ws + OFF_EW_C; deg = ws + OFF_DEG_C; cnt = (int*)(ws + OFF_CNT_C);
    } else {
        idx = i - E_CELL; if (idx >= E_DRUG) return;
        x = xd; edges = ed; N = N_DRUG; E = E_DRUG;
        ew = ws + OFF_EW_D; deg = ws + OFF_DEG_D; cnt = (int*)(ws + OFF_CNT_D);
    }
    int r = edges[idx], c = edges[E + idx];
    float w = x[(size_t)r * N + c];
    ew[idx] = w;
    unsafeAtomicAdd(&deg[c], w);
    atomicAdd(&cnt[c], 1);
}

// ---------------- K3: dinv (blocks 0..47) + exclusive scan (blocks 48,49) ----------------
__global__ __launch_bounds__(256) void k_scan2(float* ws) {
    int bid = blockIdx.x, t = threadIdx.x;
    if (bid < 48) {
        int i = bid * 256 + t;
        float d = ws[i];
        ws[i] = d > 0.f ? rsqrtf(fmaxf(d, 1e-30f)) : 0.f;
        return;
    }
    const int* cnt; int* start; int N, chunk;
    if (bid == 48) { cnt = (const int*)(ws + OFF_CNT_C); start = (int*)(ws + OFF_START_C); N = N_CELL; chunk = 32; }
    else           { cnt = (const int*)(ws + OFF_CNT_D); start = (int*)(ws + OFF_START_D); N = N_DRUG; chunk = 16; }
    __shared__ int sums[256];
    int base = t * chunk;
    int s = 0;
    for (int j = 0; j < chunk; ++j) s += cnt[base + j];
    sums[t] = s; __syncthreads();
    for (int off = 1; off < 256; off <<= 1) {
        int v = (t >= off) ? sums[t - off] : 0;
        __syncthreads();
        sums[t] += v;
        __syncthreads();
    }
    int run = sums[t] - s;
    for (int j = 0; j < chunk; ++j) { start[base + j] = run; run += cnt[base + j]; }
    if (t == 255) start[N] = run;
}

// ---------------- K4: GEMM via global_load_lds (m97-style) + CSR fill co-scheduled ----
// GEMM: 128x128 tile, BK=64, K-chunk 1024 (16 steps). LDS 48KB single-buffered:
//   A[128 rows][64 k] f32 (32KB, offset 0), B[128 cols][64 k] bf16 (16KB, offset 32768).
// Staging: global_load_lds width 16, LINEAR dest; bank-conflict-free reads achieved by
// inverse-swizzling the per-lane GLOBAL source (rule #21 / m201 stage pattern):
//   LDS_A[r][m] = A[r][m ^ (r&7)]  (m = 16B seg)  -> read byte (r*256+s*16)^((r&7)<<4)
//   LDS_B[c][m] = B[c][m ^ (c&7)]                 -> read byte 32768+((c*128+s*16)^((c&7)<<4))
// 4 waves, wave tile 64x64 (wm=wv>>1, wn=wv&1), acc[4][4], A packed f32->bf16 at read.
// cell: 64 mt x 8 ch = 512 blocks; drug: 32 x 4 = 128; fill: 1536. Grid 2176.
__global__ __launch_bounds__(256, 3) void k_gemmfill(const float* __restrict__ xc, const float* __restrict__ xd,
                                                      const unsigned short* __restrict__ wtc,
                                                      const unsigned short* __restrict__ wtd,
                                                      const int* __restrict__ ec, const int* __restrict__ ed,
                                                      float* __restrict__ ws) {
    int bid = blockIdx.x, t = threadIdx.x;
    if (bid >= 640) {
        // ---------------- CSR fill path ----------------
        int i = (bid - 640) * 256 + t;
        const int* edges; const float* ew; const float* dinv; const int* start;
        int* cur; int* srow; float* scoef; int E, idx;
        if (i < E_CELL) {
            idx = i; edges = ec; E = E_CELL;
            ew = ws + OFF_EW_C; dinv = ws + OFF_DEG_C; start = (const int*)(ws + OFF_START_C);
            cur = (int*)(ws + OFF_CUR_C); srow = (int*)(ws + OFF_SROW_C); scoef = ws + OFF_SCOEF_C;
        } else {
            idx = i - E_CELL; if (idx >= E_DRUG) return;
            edges = ed; E = E_DRUG;
            ew = ws + OFF_EW_D; dinv = ws + OFF_DEG_D; start = (const int*)(ws + OFF_START_D);
            cur = (int*)(ws + OFF_CUR_D); srow = (int*)(ws + OFF_SROW_D); scoef = ws + OFF_SCOEF_D;
        }
        int r = edges[idx], c = edges[E + idx];
        float coef = dinv[r] * ew[idx] * dinv[c];
        int slot = start[c] + atomicAdd(&cur[c], 1);
        srow[slot] = r;
        scoef[slot] = coef;
        return;
    }
    // ---------------- GEMM path ----------------
    const float* x; const unsigned short* wt; float* h; int K, mt, ch;
    if (bid < 512) { x = xc; wt = wtc; h = ws + OFF_H_C; K = N_CELL; mt = bid >> 3; ch = bid & 7; }
    else { int b = bid - 512; x = xd; wt = wtd; h = ws + OFF_H_D; K = N_DRUG; mt = b >> 2; ch = b & 3; }
    int kch = ch << 10;                                  // K-chunk base (1024 elements)

    __shared__ alignas(16) unsigned char smem[49152];
    int lane = t & 63, wv = t >> 6;
    int l15 = lane & 15, l4 = lane >> 4;
    int wm = wv >> 1, wn = wv & 1;

    f32x4 acc[4][4] = {};

    // ---- per-lane pre-swizzled global source addresses ----
    // A even/odd window bases (window = 4 rows x 64 f32 = 1KB; wave w owns windows w*8..w*8+7)
    int rloc = lane >> 4;                                // 0..3
    const char* aE = (const char*)x
        + ((size_t)(mt * 128 + 32 * wv + rloc) * K + kch) * 4
        + (((lane & 15) ^ rloc) << 4);
    const char* aO = (const char*)x
        + ((size_t)(mt * 128 + 32 * wv + 4 + rloc) * K + kch) * 4
        + (((lane & 15) ^ (4 + rloc)) << 4);
    // B base (window = 8 cols x 64 bf16 = 1KB; wave w owns windows w*4..w*4+3)
    int cloc = lane >> 3;                                // 0..7
    const char* bB = (const char*)wt
        + ((size_t)(32 * wv + cloc) * K + kch) * 2
        + (((lane & 7) ^ cloc) << 4);

    unsigned char* ldsA = smem + wv * 8192;              // windows w*8.. (8 x 1KB)
    unsigned char* ldsB = smem + 32768 + wv * 4096;      // windows w*4.. (4 x 1KB)
    size_t aWinStride = (size_t)K * 32;                  // 8 rows * K * 4B
    size_t bWinStride = (size_t)K * 16;                  // 8 cols * K * 2B

#pragma unroll 1
    for (int kt = 0; kt < 16; ++kt) {
        // ---- stage: 12 global_load_lds per wave ----
        size_t ka = (size_t)kt * 256, kb = (size_t)kt * 128;
#pragma unroll
        for (int q = 0; q < 4; ++q) {
            gload16(aE + q * aWinStride + ka, ldsA + (2 * q) * 1024);
            gload16(aO + q * aWinStride + ka, ldsA + (2 * q + 1) * 1024);
        }
#pragma unroll
        for (int jr = 0; jr < 4; ++jr)
            gload16(bB + jr * bWinStride + kb, ldsB + jr * 1024);
        __syncthreads();
        // ---- compute: 32 MFMA per wave ----
#pragma unroll
        for (int kk = 0; kk < 2; ++kk) {
            s16x8 af[4], bf[4];
#pragma unroll
            for (int m = 0; m < 4; ++m) {
                int r = wm * 64 + m * 16 + l15;
                int s1 = kk * 8 + l4 * 2;
                unsigned xo = (unsigned)(r & 7) << 4;
                float4 q0 = *(const float4*)&smem[((unsigned)(r * 256 + s1 * 16)) ^ xo];
                float4 q1 = *(const float4*)&smem[((unsigned)(r * 256 + s1 * 16 + 16)) ^ xo];
                af[m] = pack8(q0, q1);
            }
#pragma unroll
            for (int n = 0; n < 4; ++n) {
                int c = wn * 64 + n * 16 + l15;
                int sb = kk * 4 + l4;
                bf[n] = *(const s16x8*)&smem[32768u + (((unsigned)(c * 128 + sb * 16)) ^ ((unsigned)(c & 7) << 4))];
            }
#pragma unroll
            for (int m = 0; m < 4; ++m)
#pragma unroll
                for (int n = 0; n < 4; ++n)
                    acc[m][n] = __builtin_amdgcn_mfma_f32_16x16x32_bf16(af[m], bf[n], acc[m][n], 0, 0, 0);
        }
        __syncthreads();
    }
    // ---- epilogue: atomic-accumulate partials. D layout: col=lane&15, row=(lane>>4)*4+j ----
#pragma unroll
    for (int m = 0; m < 4; ++m)
#pragma unroll
        for (int n = 0; n < 4; ++n) {
            int col = wn * 64 + n * 16 + l15;
            int row = mt * 128 + wm * 64 + m * 16 + l4 * 4;
#pragma unroll
            for (int j = 0; j < 4; ++j)
                unsafeAtomicAdd(&h[(size_t)(row + j) * DOUT + col], acc[m][n][j]);
        }
}

// ---------------- K5: CSR gather + self loop + bias + relu ----------------
__global__ __launch_bounds__(256) void k_gather(const float* __restrict__ ws,
                                                const float* __restrict__ bc, const float* __restrict__ bd,
                                                float* __restrict__ out) {
    int wv = threadIdx.x >> 6, lane = threadIdx.x & 63;
    int g = blockIdx.x * 4 + wv;
    const float* h; const int* srow; const float* scoef; const int* start; const float* dinv;
    const float* bvec; float* outp; int node;
    if (g < N_CELL) {
        node = g; h = ws + OFF_H_C; srow = (const int*)(ws + OFF_SROW_C); scoef = ws + OFF_SCOEF_C;
        start = (const int*)(ws + OFF_START_C); dinv = ws + OFF_DEG_C; bvec = bc; outp = out;
    } else {
        node = g - N_CELL; if (node >= N_DRUG) return;
        h = ws + OFF_H_D; srow = (const int*)(ws + OFF_SROW_D); scoef = ws + OFF_SCOEF_D;
        start = (const int*)(ws + OFF_START_D); dinv = ws + OFF_DEG_D; bvec = bd;
        outp = out + (size_t)N_CELL * DOUT;
    }
    float di = dinv[node], sc = di * di;
    float2 v = ((const float2*)(h + (size_t)node * DOUT))[lane];
    float ax = sc * v.x, ay = sc * v.y;
    int s0 = start[node], s1 = start[node + 1];
    int e = s0;
    for (; e + 3 < s1; e += 4) {
        int r0 = srow[e];     float c0 = scoef[e];
        int r1 = srow[e + 1]; float c1 = scoef[e + 1];
        int r2 = srow[e + 2]; float c2 = scoef[e + 2];
        int r3 = srow[e + 3]; float c3 = scoef[e + 3];
        float2 u0 = ((const float2*)(h + (size_t)r0 * DOUT))[lane];
        float2 u1 = ((const float2*)(h + (size_t)r1 * DOUT))[lane];
        float2 u2 = ((const float2*)(h + (size_t)r2 * DOUT))[lane];
        float2 u3 = ((const float2*)(h + (size_t)r3 * DOUT))[lane];
        ax += c0 * u0.x + c1 * u1.x + c2 * u2.x + c3 * u3.x;
        ay += c0 * u0.y + c1 * u1.y + c2 * u2.y + c3 * u3.y;
    }
    for (; e < s1; ++e) {
        int r = srow[e]; float cf = scoef[e];
        float2 u = ((const float2*)(h + (size_t)r * DOUT))[lane];
        ax += cf * u.x; ay += cf * u.y;
    }
    float2 bb = ((const float2*)bvec)[lane];
    ax = fmaxf(ax + bb.x, 0.f);
    ay = fmaxf(ay + bb.y, 0.f);
    float2 o; o.x = ax; o.y = ay;
    ((float2*)outp)[(size_t)node * 64 + lane] = o;
}

// ---------------- host ----------------
extern "C" void kernel_launch(void* const* d_in, const int* in_sizes, int n_in,
                              void* d_out, int out_size, void* d_ws, size_t ws_size,
                              hipStream_t stream) {
    const float* cell_feat = (const float*)d_in[0];
    const int*   cell_edge = (const int*)d_in[1];
    const float* W_cell    = (const float*)d_in[2];
    const float* b_cell    = (const float*)d_in[3];
    const float* drug_feat = (const float*)d_in[4];
    const int*   drug_edge = (const int*)d_in[5];
    const float* W_drug    = (const float*)d_in[6];
    const float* b_drug    = (const float*)d_in[7];
    float* out = (float*)d_out;
    float* ws  = (float*)d_ws;
    unsigned short* wtc = (unsigned short*)((char*)d_ws + WT_C_BYTE);
    unsigned short* wtd = (unsigned short*)((char*)d_ws + WT_D_BYTE);

    k_prep<<<3216, 256, 0, stream>>>(W_cell, W_drug, wtc, wtd, ws);
    k_edge<<<(E_CELL + E_DRUG) / 256, 256, 0, stream>>>(cell_feat, cell_edge, drug_feat, drug_edge, ws);
    k_scan2<<<50, 256, 0, stream>>>(ws);
    k_gemmfill<<<2176, 256, 0, stream>>>(cell_feat, drug_feat, wtc, wtd, cell_edge, drug_edge, ws);
    k_gather<<<3072, 256, 0, stream>>>(ws, b_cell, b_drug, out);
}